// Round 10
// baseline (1369.085 us; speedup 1.0000x reference)
//
#include <hip/hip_runtime.h>
#include <hip/hip_bf16.h>
#include <math.h>

#define HID   1024
#define IN_D  600
#define IN_DP 640      // 600 padded to 10 x BK=64 chunks
#define BATCH 2048
#define TSTEP 20
#define BT    (BATCH * TSTEP)   // 40960
#define G3    3072

typedef __attribute__((ext_vector_type(8))) short bf16x8;
typedef __attribute__((ext_vector_type(4))) float f32x4;

#define GLB(p) ((const __attribute__((address_space(1))) void*)(p))
#define LDS(p) ((__attribute__((address_space(3))) void*)(p))

__device__ __forceinline__ short f2bf(float f) {
    __hip_bfloat16 b = __float2bfloat16(f);
    return *(short*)&b;
}
__device__ __forceinline__ float bf2f(short s) {
    __hip_bfloat16 b = *(__hip_bfloat16*)&s;
    return __bfloat162float(b);
}

// ---------------------------------------------------------------------------
// Input projection v2 (UNCHANGED from round 8: 204 us, MfmaUtil 34%,
// bank conflicts 0 — attribution isolation for the gru_step v12 change).
// ---------------------------------------------------------------------------
__global__ __launch_bounds__(512) void gemm_input2(const short* __restrict__ X,
                                                   const short* __restrict__ Wih_r,
                                                   const float* __restrict__ b_ih,
                                                   short* __restrict__ gx) {
    __shared__ short LDSF[4 * 20480];   // buf b at b*20480: sA@0 (16K), sB@8192 (24K)

    const int id    = blockIdx.x;
    const int xcd   = id & 7;
    const int local = id >> 3;          // 0..639
    const int jsub  = local & 1;
    const int mblk  = local >> 1;       // 0..319
    const int j0 = (xcd * 2 + jsub) * 64;
    const int m0 = mblk * 128;

    const int tid  = threadIdx.x;
    const int wave = tid >> 6;          // 0..7
    const int lane = tid & 63;
    const int wm = (wave >> 2) * 64;    // m-group: 0 or 64
    const int jg = wave & 3;            // j-group: 16 j each
    const int fm = lane & 15;
    const int fq = lane >> 4;

    const int srow8 = lane >> 3;                // 0..7
    const int sxor  = ((lane & 7) ^ srow8) * 8; // inverse-swizzled col (shorts)

    const short* Wblk = Wih_r + (size_t)(j0 * 3) * IN_DP;   // 192 rows, K=640

    f32x4 acc[4][3] = {};    // [m-frag][gate]

    // 5 uniform global_load_lds per wave per chunk (2 sA + 3 sB)
    auto stage = [&](int kc, int bsel) {
        int k0 = kc * 64;
        short* base = LDSF + bsel * 20480;
#pragma unroll
        for (int i = 0; i < 2; ++i) {
            int row0 = wave * 16 + i * 8;
            const short* g = X + (size_t)(m0 + row0 + srow8) * IN_DP + k0 + sxor;
            __builtin_amdgcn_global_load_lds(GLB(g), LDS(base + row0 * 64), 16, 0, 0);
        }
#pragma unroll
        for (int i = 0; i < 3; ++i) {
            int row0 = wave * 24 + i * 8;
            const short* g = Wblk + (size_t)(row0 + srow8) * IN_DP + k0 + sxor;
            __builtin_amdgcn_global_load_lds(GLB(g), LDS(base + 8192 + row0 * 64), 16, 0, 0);
        }
    };

    stage(0, 0);
    stage(1, 1);

#pragma unroll
    for (int ic = 0; ic < 10; ++ic) {
        if (ic < 8) stage(ic + 2, (ic + 2) & 3);
        if (ic < 8)       asm volatile("s_waitcnt vmcnt(10)" : : : "memory");
        else if (ic == 8) asm volatile("s_waitcnt vmcnt(5)"  : : : "memory");
        else              asm volatile("s_waitcnt vmcnt(0)"  : : : "memory");
        __builtin_amdgcn_s_barrier();
        __builtin_amdgcn_sched_barrier(0);

        short* buf = LDSF + (ic & 3) * 20480;

#pragma unroll
        for (int kk = 0; kk < 2; ++kk) {
            bf16x8 af[4], bg[3];
            const int cbase = kk * 32 + fq * 8;
            const int csw = cbase ^ ((fm & 7) * 8);
#pragma unroll
            for (int mi = 0; mi < 4; ++mi)
                af[mi] = *(const bf16x8*)(&buf[(wm + mi * 16 + fm) * 64 + csw]);
#pragma unroll
            for (int g = 0; g < 3; ++g)
                bg[g] = *(const bf16x8*)(&buf[8192 + (jg * 48 + g * 16 + fm) * 64 + csw]);
            __builtin_amdgcn_s_setprio(1);
#pragma unroll
            for (int mi = 0; mi < 4; ++mi)
#pragma unroll
                for (int g = 0; g < 3; ++g)
                    acc[mi][g] = __builtin_amdgcn_mfma_f32_16x16x32_bf16(af[mi], bg[g], acc[mi][g], 0, 0, 0);
            __builtin_amdgcn_s_setprio(0);
        }
    }

    // Epilogue: gx[gm][g*1024 + j0 + jg*16 + fm] = bf16(acc + b_ih)
    const int jl = j0 + jg * 16 + fm;
#pragma unroll
    for (int g = 0; g < 3; ++g) {
        float bias = b_ih[g * HID + jl];
#pragma unroll
        for (int mi = 0; mi < 4; ++mi) {
#pragma unroll
            for (int r = 0; r < 4; ++r) {
                int gm = m0 + wm + mi * 16 + fq * 4 + r;
                gx[(size_t)gm * G3 + g * HID + jl] = f2bf(acc[mi][g][r] + bias);
            }
        }
    }
}

// ---------------------------------------------------------------------------
// Fused recurrent step v12: h read DIRECT from global (no sA staging).
// Fusion arc (v8/v10/v11) abandoned: all variants lose to per-step launches
// (coherence/locality losses > 16 us/step boundary tax). v12 attacks the
// per-chunk cost instead (calibrated ~2450 cyc vs 1344-cyc LDS floor):
//  - af (h fragments) = plain global bf16x8 loads. h is read-only within a
//    step; the 4x j-wave LDS amplification becomes L1/L2 hits. LDS reads
//    drop 112 -> 48 per chunk; stage 5 -> 3 loads/wave.
//  - sB (Wr) pipeline UNCHANGED: NB=4 x 24 KB, lead-2, issue -> counted
//    vmcnt -> s_barrier -> read (proven race-audited template).
//  - sGX now a DEDICATED 48 KB region (LDS total 96+48 = 144 KB), prefetched
//    once at prologue — no tail-overlay; drained by iter-2's vmcnt(6).
//  - hsnap deleted: epilogue reads hb_in directly (immutable; bit-identical).
// vmcnt ladder (stage=3/wave; prologue order W0,W1,sGX6):
//   it0: +W2 -> 15 outst, retire W0 -> vmcnt(12)
//   it1: +W3 -> 15, retire W1 -> vmcnt(12)
//   it2: +W4 -> 15, retire W2 (and older sGX) -> vmcnt(6)
//   it3..13: 9, retire W(ic) -> vmcnt(6);  it14: 6 -> vmcnt(3);  it15: vmcnt(0)
// af loads are compiler-tracked and consumed in-iteration (issued after the
// post-barrier sched_barrier, pinned BEFORE the stage issue by a second
// sched_barrier) so the manual ladder counts only stage loads.
// Swizzle identity: old path returned global[row][cbase] after double-XOR;
// direct load of cbase is value-identical.
// ---------------------------------------------------------------------------
__global__ __launch_bounds__(512) void gru_step(const short* __restrict__ hb_in,
                                                const short* __restrict__ Wr,
                                                const short* __restrict__ gx,
                                                const float* __restrict__ b_hh,
                                                short* __restrict__ hb_out,
                                                float* __restrict__ out,
                                                int t, int last) {
    __shared__ short LDSF[4 * 12288 + 3 * 8192];  // 96 KB sB bufs + 48 KB sGX

    const int id   = blockIdx.x;
    const int xcd  = id & 7;
    const int rest = id >> 3;           // 0..31
    const int jsub = rest & 1;
    const int mblk = rest >> 1;         // 0..15
    const int j0 = (xcd * 2 + jsub) * 64;
    const int m0 = mblk * 128;

    const int tid  = threadIdx.x;
    const int wave = tid >> 6;          // 0..7
    const int lane = tid & 63;
    const int wm = (wave >> 2) * 64;    // m-group: 0 or 64
    const int jg = wave & 3;            // j-group: 16 j each
    const int fm = lane & 15;
    const int fq = lane >> 4;

    const int srow8 = lane >> 3;               // 0..7 (row within 8-row group)
    const int sxor  = ((lane & 7) ^ srow8) * 8; // inverse-swizzled col (shorts)

    const short* Wblk = Wr + (size_t)(j0 * 3) * HID;   // 192 rows, K=1024
    const short* gxt  = gx + (size_t)t * BATCH * G3;

    f32x4 acc[4][3] = {};    // [m-frag][gate]

    // 3 Wr global_load_lds per wave per chunk — uniform across waves.
    auto stage = [&](int kc, int bsel) {
        int k0 = kc * 64;
        short* base = LDSF + bsel * 12288;
#pragma unroll
        for (int i = 0; i < 3; ++i) {   // 24 instrs over 8 waves
            int row0 = wave * 24 + i * 8;
            const short* g = Wblk + (size_t)(row0 + srow8) * HID + k0 + sxor;
            __builtin_amdgcn_global_load_lds(GLB(g), LDS(base + row0 * 64), 16, 0, 0);
        }
    };

    // h fragment row bases (this wave's 4 m-frag rows for ds-free af loads)
    const short* hrow[4];
#pragma unroll
    for (int mi = 0; mi < 4; ++mi)
        hrow[mi] = hb_in + (size_t)(m0 + wm + mi * 16 + fm) * HID + fq * 8;

    const int jj = jg * 16 + fm;        // block-local j (0..63)

    // ---- prologue: W chunks 0,1 then the full 48 KB sGX (6 instrs/wave) ----
    stage(0, 0);
    stage(1, 1);
#pragma unroll
    for (int i = 0; i < 6; ++i) {
        int q = wave * 6 + i;           // 0..47: gate q>>4, rows (q&15)*8..+7
        int g = q >> 4;
        int row0 = (q & 15) * 8;
        const short* src = gxt + (size_t)(m0 + row0 + srow8) * G3 + g * HID + j0 + sxor;
        __builtin_amdgcn_global_load_lds(GLB(src), LDS(LDSF + 49152 + q * 512), 16, 0, 0);
    }

#pragma unroll
    for (int ic = 0; ic < 16; ++ic) {
        if (ic < 14) stage(ic + 2, (ic + 2) & 3);      // lead-2 (proven WAR-safe)
        if (ic < 2)       asm volatile("s_waitcnt vmcnt(12)" : : : "memory");
        else if (ic < 14) asm volatile("s_waitcnt vmcnt(6)"  : : : "memory");
        else if (ic == 14) asm volatile("s_waitcnt vmcnt(3)" : : : "memory");
        else               asm volatile("s_waitcnt vmcnt(0)" : : : "memory");
        __builtin_amdgcn_s_barrier();
        __builtin_amdgcn_sched_barrier(0);        // no sB reads hoist above publish

        short* buf = LDSF + (ic & 3) * 12288;
        const int k0 = ic * 64;

        // issue ALL af global loads first (compiler-tracked; consumed below)
        bf16x8 af0[4], af1[4];
#pragma unroll
        for (int mi = 0; mi < 4; ++mi) {
            af0[mi] = *(const bf16x8*)(hrow[mi] + k0);
            af1[mi] = *(const bf16x8*)(hrow[mi] + k0 + 32);
        }
        __builtin_amdgcn_sched_barrier(0);        // af issued before next stage

#pragma unroll
        for (int kk = 0; kk < 2; ++kk) {
            bf16x8 bg[3];
            const int cbase = kk * 32 + fq * 8;
            const int csw = cbase ^ ((fm & 7) * 8);   // swizzled read col
#pragma unroll
            for (int g = 0; g < 3; ++g)
                bg[g] = *(const bf16x8*)(&buf[(jg * 48 + g * 16 + fm) * 64 + csw]);
            __builtin_amdgcn_s_setprio(1);
#pragma unroll
            for (int mi = 0; mi < 4; ++mi)
#pragma unroll
                for (int g = 0; g < 3; ++g)
                    acc[mi][g] = __builtin_amdgcn_mfma_f32_16x16x32_bf16(
                        kk ? af1[mi] : af0[mi], bg[g], acc[mi][g], 0, 0, 0);
            __builtin_amdgcn_s_setprio(0);
        }
    }

    // sGX was drained by iter-2's vmcnt(6); one barrier so all waves' MFMA
    // phase is done before epilogue (sGX region is stable — written once).
    __builtin_amdgcn_s_barrier();

    const short* sGX = LDSF + 49152;    // 48 KB dedicated
    const int jlane = j0 + jj;
    const float bh_r = b_hh[jlane];
    const float bh_i = b_hh[HID + jlane];
    const float bh_n = b_hh[2 * HID + jlane];

#pragma unroll
    for (int mi = 0; mi < 4; ++mi) {
#pragma unroll
        for (int r = 0; r < 4; ++r) {
            int mloc = wm + mi * 16 + fq * 4 + r;
            int gm = m0 + mloc;
            int jsw = jj ^ ((mloc & 7) * 8);          // sGX swizzled col
            float xr = bf2f(sGX[        mloc * 64 + jsw]);
            float xi = bf2f(sGX[ 8192 + mloc * 64 + jsw]);
            float xn = bf2f(sGX[16384 + mloc * 64 + jsw]);

            float rg = 1.0f / (1.0f + __expf(-(xr + acc[mi][0][r] + bh_r)));
            float ig = 1.0f / (1.0f + __expf(-(xi + acc[mi][1][r] + bh_i)));
            float ng = tanhf(xn + rg * (acc[mi][2][r] + bh_n));

            // h read direct from immutable hb_in (replaces hsnap; same value)
            float h  = bf2f(hb_in[(size_t)gm * HID + jlane]);
            float hy = ng + ig * (h - ng);
            size_t idx = (size_t)gm * HID + jlane;
            hb_out[idx] = f2bf(hy);
            if (last) out[idx] = hy;
        }
    }
}

// x [b][t][600] fp32 -> x_bf [t*B + b][640] bf16 zero-padded (transpose)
__global__ __launch_bounds__(256) void cvt_x(const float* __restrict__ X, short* __restrict__ Xb) {
    int rd = blockIdx.x;             // dst row = t*BATCH + b
    int tt = rd >> 11;               // /2048
    int b  = rd & (BATCH - 1);
    const float* s = X + ((size_t)b * TSTEP + tt) * IN_D;
    short* d = Xb + (size_t)rd * IN_DP;
    for (int c = threadIdx.x; c < IN_DP; c += 256)
        d[c] = (c < IN_D) ? f2bf(s[c]) : (short)0;
}

// W_ih -> gate-block-interleaved bf16 [3072][640]:
// dst row jb*48+g*16+ji = W_ih[g*1024 + jb*16 + ji], zero-padded K 600->640
__global__ __launch_bounds__(256) void cvt_wih_r(const float* __restrict__ W, short* __restrict__ Wb) {
    int n  = blockIdx.x;             // dst row 0..3071
    int jb = n / 48;
    int rem = n - jb * 48;
    int g  = rem >> 4;
    int ji = rem & 15;
    const float* s = W + (size_t)(g * HID + jb * 16 + ji) * IN_D;
    short* d = Wb + (size_t)n * IN_DP;
    for (int c = threadIdx.x; c < IN_DP; c += 256)
        d[c] = (c < IN_D) ? f2bf(s[c]) : (short)0;
}

// W_hh -> Wr gate-block-interleaved bf16: Wr[jb*48+g*16+ji] = Whh[g*1024+jb*16+ji]
__global__ __launch_bounds__(256) void cvt_whh(const float* __restrict__ W, short* __restrict__ Wr) {
    int n  = blockIdx.x;             // dst row 0..3071
    int jb = n / 48;
    int rem = n - jb * 48;
    int g  = rem >> 4;
    int ji = rem & 15;
    const float* s = W + (size_t)(g * HID + jb * 16 + ji) * HID;
    short* d = Wr + (size_t)n * HID;
    for (int c = threadIdx.x; c < HID; c += 256) d[c] = f2bf(s[c]);
}

extern "C" void kernel_launch(void* const* d_in, const int* in_sizes, int n_in,
                              void* d_out, int out_size, void* d_ws, size_t ws_size,
                              hipStream_t stream) {
    const float* x    = (const float*)d_in[0];  // [B, T, IN_D]
    const float* W_ih = (const float*)d_in[1];  // [3H, IN_D]
    const float* b_ih = (const float*)d_in[2];
    const float* W_hh = (const float*)d_in[3];  // [3H, HID]
    const float* b_hh = (const float*)d_in[4];
    float* out = (float*)d_out;                 // [B, HID]

    char* p = (char*)d_ws;
    short* gx     = (short*)p;  p += (size_t)BT * G3 * 2;       // 251.7 MB, [t][b][3H]
    short* x_bf   = (short*)p;  p += (size_t)BT * IN_DP * 2;    //  52.4 MB, [t][b][640]
    short* hb0    = (short*)p;  p += (size_t)BATCH * HID * 2;   //   4.2 MB
    short* hb1    = (short*)p;  p += (size_t)BATCH * HID * 2;   //   4.2 MB
    short* Wih_r  = (short*)p;  p += (size_t)G3 * IN_DP * 2;    //   3.9 MB
    short* Whh_r  = (short*)p;  p += (size_t)G3 * HID * 2;      //   6.3 MB
    // total ~323 MB

    cvt_wih_r<<<G3, 256, 0, stream>>>(W_ih, Wih_r);
    cvt_whh<<<G3, 256, 0, stream>>>(W_hh, Whh_r);
    cvt_x<<<BT, 256, 0, stream>>>(x, x_bf);
    hipMemsetAsync(hb0, 0, (size_t)BATCH * HID * 2, stream);

    // Input projection, counted-vmcnt pipeline (5120 blocks x 512 threads)
    gemm_input2<<<5120, 512, 0, stream>>>(x_bf, Wih_r, b_ih, gx);

    // 20 fused recurrent steps (256 blocks x 512 threads, XCD-swizzled)
    for (int t = 0; t < TSTEP; ++t) {
        const short* hin = (t & 1) ? hb1 : hb0;
        short* hout      = (t & 1) ? hb0 : hb1;
        gru_step<<<256, 512, 0, stream>>>(hin, Whh_r, gx, b_hh,
                                          hout, out, t, t == TSTEP - 1 ? 1 : 0);
    }
}

// Round 11
// 1245.328 us; speedup vs baseline: 1.0994x; 1.0994x over previous
//
#include <hip/hip_runtime.h>
#include <hip/hip_bf16.h>
#include <math.h>

#define HID   1024
#define IN_D  600
#define IN_DP 640      // 600 padded to 10 x BK=64 chunks
#define BATCH 2048
#define TSTEP 20
#define BT    (BATCH * TSTEP)   // 40960
#define G3    3072

typedef __attribute__((ext_vector_type(8))) short bf16x8;
typedef __attribute__((ext_vector_type(4))) float f32x4;

#define GLB(p) ((const __attribute__((address_space(1))) void*)(p))
#define LDS(p) ((__attribute__((address_space(3))) void*)(p))

__device__ __forceinline__ short f2bf(float f) {
    __hip_bfloat16 b = __float2bfloat16(f);
    return *(short*)&b;
}
__device__ __forceinline__ float bf2f(short s) {
    __hip_bfloat16 b = *(__hip_bfloat16*)&s;
    return __bfloat162float(b);
}

// ---------------------------------------------------------------------------
// Input projection v2 (UNCHANGED from round 8: 204 us, MfmaUtil 34%,
// bank conflicts 0 — attribution isolation for the gru_step v13 change).
// ---------------------------------------------------------------------------
__global__ __launch_bounds__(512) void gemm_input2(const short* __restrict__ X,
                                                   const short* __restrict__ Wih_r,
                                                   const float* __restrict__ b_ih,
                                                   short* __restrict__ gx) {
    __shared__ short LDSF[4 * 20480];   // buf b at b*20480: sA@0 (16K), sB@8192 (24K)

    const int id    = blockIdx.x;
    const int xcd   = id & 7;
    const int local = id >> 3;          // 0..639
    const int jsub  = local & 1;
    const int mblk  = local >> 1;       // 0..319
    const int j0 = (xcd * 2 + jsub) * 64;
    const int m0 = mblk * 128;

    const int tid  = threadIdx.x;
    const int wave = tid >> 6;          // 0..7
    const int lane = tid & 63;
    const int wm = (wave >> 2) * 64;    // m-group: 0 or 64
    const int jg = wave & 3;            // j-group: 16 j each
    const int fm = lane & 15;
    const int fq = lane >> 4;

    const int srow8 = lane >> 3;                // 0..7
    const int sxor  = ((lane & 7) ^ srow8) * 8; // inverse-swizzled col (shorts)

    const short* Wblk = Wih_r + (size_t)(j0 * 3) * IN_DP;   // 192 rows, K=640

    f32x4 acc[4][3] = {};    // [m-frag][gate]

    // 5 uniform global_load_lds per wave per chunk (2 sA + 3 sB)
    auto stage = [&](int kc, int bsel) {
        int k0 = kc * 64;
        short* base = LDSF + bsel * 20480;
#pragma unroll
        for (int i = 0; i < 2; ++i) {
            int row0 = wave * 16 + i * 8;
            const short* g = X + (size_t)(m0 + row0 + srow8) * IN_DP + k0 + sxor;
            __builtin_amdgcn_global_load_lds(GLB(g), LDS(base + row0 * 64), 16, 0, 0);
        }
#pragma unroll
        for (int i = 0; i < 3; ++i) {
            int row0 = wave * 24 + i * 8;
            const short* g = Wblk + (size_t)(row0 + srow8) * IN_DP + k0 + sxor;
            __builtin_amdgcn_global_load_lds(GLB(g), LDS(base + 8192 + row0 * 64), 16, 0, 0);
        }
    };

    stage(0, 0);
    stage(1, 1);

#pragma unroll
    for (int ic = 0; ic < 10; ++ic) {
        if (ic < 8) stage(ic + 2, (ic + 2) & 3);
        if (ic < 8)       asm volatile("s_waitcnt vmcnt(10)" : : : "memory");
        else if (ic == 8) asm volatile("s_waitcnt vmcnt(5)"  : : : "memory");
        else              asm volatile("s_waitcnt vmcnt(0)"  : : : "memory");
        __builtin_amdgcn_s_barrier();
        __builtin_amdgcn_sched_barrier(0);

        short* buf = LDSF + (ic & 3) * 20480;

#pragma unroll
        for (int kk = 0; kk < 2; ++kk) {
            bf16x8 af[4], bg[3];
            const int cbase = kk * 32 + fq * 8;
            const int csw = cbase ^ ((fm & 7) * 8);
#pragma unroll
            for (int mi = 0; mi < 4; ++mi)
                af[mi] = *(const bf16x8*)(&buf[(wm + mi * 16 + fm) * 64 + csw]);
#pragma unroll
            for (int g = 0; g < 3; ++g)
                bg[g] = *(const bf16x8*)(&buf[8192 + (jg * 48 + g * 16 + fm) * 64 + csw]);
            __builtin_amdgcn_s_setprio(1);
#pragma unroll
            for (int mi = 0; mi < 4; ++mi)
#pragma unroll
                for (int g = 0; g < 3; ++g)
                    acc[mi][g] = __builtin_amdgcn_mfma_f32_16x16x32_bf16(af[mi], bg[g], acc[mi][g], 0, 0, 0);
            __builtin_amdgcn_s_setprio(0);
        }
    }

    // Epilogue: gx[gm][g*1024 + j0 + jg*16 + fm] = bf16(acc + b_ih)
    const int jl = j0 + jg * 16 + fm;
#pragma unroll
    for (int g = 0; g < 3; ++g) {
        float bias = b_ih[g * HID + jl];
#pragma unroll
        for (int mi = 0; mi < 4; ++mi) {
#pragma unroll
            for (int r = 0; r < 4; ++r) {
                int gm = m0 + wm + mi * 16 + fq * 4 + r;
                gx[(size_t)gm * G3 + g * HID + jl] = f2bf(acc[mi][g][r] + bias);
            }
        }
    }
}

// ---------------------------------------------------------------------------
// Fused recurrent step v13: register-prefetched af at LEAD-2.
// v12 post-mortem (1369 us): af loads issued after the barrier and consumed
// immediately -> the compiler's own waitcnt for af (newest in program order)
// transitively retired stage(ic+1) AND stage(ic+2) -> pipeline collapsed to
// negative lead, one serialized L2 round-trip per chunk (8550 cyc/chunk).
// v13 fixes the schedule, keeps the (numerics-proven) v12 dataflow:
//  - af(ic+2) prefetched into a 3-deep register rotation afr[3][8] at the
//    TOP of iter ic, BEFORE stage(ic+2). Ladder (induction-verified):
//    after iter-k wait, outstanding = {af(k+1),st(k+1),af(k+2),st(k+2)} = 22.
//    iters 0..13: vmcnt(22) retires af(k)+st(k); iter14: vmcnt(11);
//    iter15: vmcnt(0). Compiler's af-wait (~32) is now LOOSER than ours ->
//    no-op; true lead-2 preserved for both af and sB.
//  - LDS reads 112 -> 48 b128/chunk (bg only); stage 5 -> 3 loads/wave.
//  - sGX dedicated 48 KB, loaded at prologue (retired by iter-0's wait,
//    published by iter-1+ barriers). LDS = 96 KB sB bufs + 48 KB sGX.
//  - epilogue h read direct from immutable hb_in (v12-proven identical).
//  - afr fully-unrolled ic-loop -> all indices compile-time (rule #20).
// ---------------------------------------------------------------------------
__global__ __launch_bounds__(512) void gru_step(const short* __restrict__ hb_in,
                                                const short* __restrict__ Wr,
                                                const short* __restrict__ gx,
                                                const float* __restrict__ b_hh,
                                                short* __restrict__ hb_out,
                                                float* __restrict__ out,
                                                int t, int last) {
    __shared__ short LDSF[4 * 12288 + 3 * 8192];  // 96 KB sB bufs + 48 KB sGX

    const int id   = blockIdx.x;
    const int xcd  = id & 7;
    const int rest = id >> 3;           // 0..31
    const int jsub = rest & 1;
    const int mblk = rest >> 1;         // 0..15
    const int j0 = (xcd * 2 + jsub) * 64;
    const int m0 = mblk * 128;

    const int tid  = threadIdx.x;
    const int wave = tid >> 6;          // 0..7
    const int lane = tid & 63;
    const int wm = (wave >> 2) * 64;    // m-group: 0 or 64
    const int jg = wave & 3;            // j-group: 16 j each
    const int fm = lane & 15;
    const int fq = lane >> 4;

    const int srow8 = lane >> 3;               // 0..7 (row within 8-row group)
    const int sxor  = ((lane & 7) ^ srow8) * 8; // inverse-swizzled col (shorts)

    const short* Wblk = Wr + (size_t)(j0 * 3) * HID;   // 192 rows, K=1024
    const short* gxt  = gx + (size_t)t * BATCH * G3;

    f32x4 acc[4][3] = {};    // [m-frag][gate]
    bf16x8 afr[3][8];        // rotating af prefetch: [set][mi*2+kk]

    // 3 Wr global_load_lds per wave per chunk — uniform across waves.
    auto stage = [&](int kc, int bsel) {
        int k0 = kc * 64;
        short* base = LDSF + bsel * 12288;
#pragma unroll
        for (int i = 0; i < 3; ++i) {   // 24 instrs over 8 waves
            int row0 = wave * 24 + i * 8;
            const short* g = Wblk + (size_t)(row0 + srow8) * HID + k0 + sxor;
            __builtin_amdgcn_global_load_lds(GLB(g), LDS(base + row0 * 64), 16, 0, 0);
        }
    };

    // h fragment row bases (this wave's 4 m-frag rows; direct global af)
    const short* hrow[4];
#pragma unroll
    for (int mi = 0; mi < 4; ++mi)
        hrow[mi] = hb_in + (size_t)(m0 + wm + mi * 16 + fm) * HID + fq * 8;

    const int jj = jg * 16 + fm;        // block-local j (0..63)

    // ---- prologue: sGX (6/wave), then af0,st0, af1,st1 -------------------
#pragma unroll
    for (int i = 0; i < 6; ++i) {
        int q = wave * 6 + i;           // 0..47: gate q>>4, rows (q&15)*8..+7
        int g = q >> 4;
        int row0 = (q & 15) * 8;
        const short* src = gxt + (size_t)(m0 + row0 + srow8) * G3 + g * HID + j0 + sxor;
        __builtin_amdgcn_global_load_lds(GLB(src), LDS(LDSF + 49152 + q * 512), 16, 0, 0);
    }
#pragma unroll
    for (int mi = 0; mi < 4; ++mi) {
        afr[0][mi * 2 + 0] = *(const bf16x8*)(hrow[mi] + 0);
        afr[0][mi * 2 + 1] = *(const bf16x8*)(hrow[mi] + 32);
    }
    stage(0, 0);
#pragma unroll
    for (int mi = 0; mi < 4; ++mi) {
        afr[1][mi * 2 + 0] = *(const bf16x8*)(hrow[mi] + 64);
        afr[1][mi * 2 + 1] = *(const bf16x8*)(hrow[mi] + 96);
    }
    stage(1, 1);

#pragma unroll
    for (int ic = 0; ic < 16; ++ic) {
        // ---- lead-2 issue: af(ic+2) BEFORE stage(ic+2) -------------------
        if (ic < 14) {
            const int kc = ic + 2;
            const int s  = kc % 3;
#pragma unroll
            for (int mi = 0; mi < 4; ++mi) {
                afr[s][mi * 2 + 0] = *(const bf16x8*)(hrow[mi] + kc * 64);
                afr[s][mi * 2 + 1] = *(const bf16x8*)(hrow[mi] + kc * 64 + 32);
            }
            stage(kc, kc & 3);
        }
        // ---- counted wait (retires af(ic)+st(ic)), then publish ----------
        if (ic < 14)       asm volatile("s_waitcnt vmcnt(22)" : : : "memory");
        else if (ic == 14) asm volatile("s_waitcnt vmcnt(11)" : : : "memory");
        else               asm volatile("s_waitcnt vmcnt(0)"  : : : "memory");
        __builtin_amdgcn_s_barrier();
        __builtin_amdgcn_sched_barrier(0);    // no sB reads hoist above publish

        short* buf = LDSF + (ic & 3) * 12288;
        const int s0 = ic % 3;

#pragma unroll
        for (int kk = 0; kk < 2; ++kk) {
            bf16x8 bg[3];
            const int cbase = kk * 32 + fq * 8;
            const int csw = cbase ^ ((fm & 7) * 8);   // swizzled read col
#pragma unroll
            for (int g = 0; g < 3; ++g)
                bg[g] = *(const bf16x8*)(&buf[(jg * 48 + g * 16 + fm) * 64 + csw]);
            __builtin_amdgcn_s_setprio(1);
#pragma unroll
            for (int mi = 0; mi < 4; ++mi)
#pragma unroll
                for (int g = 0; g < 3; ++g)
                    acc[mi][g] = __builtin_amdgcn_mfma_f32_16x16x32_bf16(
                        afr[s0][mi * 2 + kk], bg[g], acc[mi][g], 0, 0, 0);
            __builtin_amdgcn_s_setprio(0);
        }
    }

    // sGX stable (written once, retired by iter-0 waits, published since
    // iter-1 barriers); one barrier so no wave races ahead into epilogue
    // while others still read buf LDS (defensive, cheap).
    __builtin_amdgcn_s_barrier();

    const short* sGX = LDSF + 49152;    // 48 KB dedicated
    const int jlane = j0 + jj;
    const float bh_r = b_hh[jlane];
    const float bh_i = b_hh[HID + jlane];
    const float bh_n = b_hh[2 * HID + jlane];

#pragma unroll
    for (int mi = 0; mi < 4; ++mi) {
#pragma unroll
        for (int r = 0; r < 4; ++r) {
            int mloc = wm + mi * 16 + fq * 4 + r;
            int gm = m0 + mloc;
            int jsw = jj ^ ((mloc & 7) * 8);          // sGX swizzled col
            float xr = bf2f(sGX[        mloc * 64 + jsw]);
            float xi = bf2f(sGX[ 8192 + mloc * 64 + jsw]);
            float xn = bf2f(sGX[16384 + mloc * 64 + jsw]);

            float rg = 1.0f / (1.0f + __expf(-(xr + acc[mi][0][r] + bh_r)));
            float ig = 1.0f / (1.0f + __expf(-(xi + acc[mi][1][r] + bh_i)));
            float ng = tanhf(xn + rg * (acc[mi][2][r] + bh_n));

            // h read direct from immutable hb_in (v12-proven identical)
            float h  = bf2f(hb_in[(size_t)gm * HID + jlane]);
            float hy = ng + ig * (h - ng);
            size_t idx = (size_t)gm * HID + jlane;
            hb_out[idx] = f2bf(hy);
            if (last) out[idx] = hy;
        }
    }
}

// x [b][t][600] fp32 -> x_bf [t*B + b][640] bf16 zero-padded (transpose)
__global__ __launch_bounds__(256) void cvt_x(const float* __restrict__ X, short* __restrict__ Xb) {
    int rd = blockIdx.x;             // dst row = t*BATCH + b
    int tt = rd >> 11;               // /2048
    int b  = rd & (BATCH - 1);
    const float* s = X + ((size_t)b * TSTEP + tt) * IN_D;
    short* d = Xb + (size_t)rd * IN_DP;
    for (int c = threadIdx.x; c < IN_DP; c += 256)
        d[c] = (c < IN_D) ? f2bf(s[c]) : (short)0;
}

// W_ih -> gate-block-interleaved bf16 [3072][640]:
// dst row jb*48+g*16+ji = W_ih[g*1024 + jb*16 + ji], zero-padded K 600->640
__global__ __launch_bounds__(256) void cvt_wih_r(const float* __restrict__ W, short* __restrict__ Wb) {
    int n  = blockIdx.x;             // dst row 0..3071
    int jb = n / 48;
    int rem = n - jb * 48;
    int g  = rem >> 4;
    int ji = rem & 15;
    const float* s = W + (size_t)(g * HID + jb * 16 + ji) * IN_D;
    short* d = Wb + (size_t)n * IN_DP;
    for (int c = threadIdx.x; c < IN_DP; c += 256)
        d[c] = (c < IN_D) ? f2bf(s[c]) : (short)0;
}

// W_hh -> Wr gate-block-interleaved bf16: Wr[jb*48+g*16+ji] = Whh[g*1024+jb*16+ji]
__global__ __launch_bounds__(256) void cvt_whh(const float* __restrict__ W, short* __restrict__ Wr) {
    int n  = blockIdx.x;             // dst row 0..3071
    int jb = n / 48;
    int rem = n - jb * 48;
    int g  = rem >> 4;
    int ji = rem & 15;
    const float* s = W + (size_t)(g * HID + jb * 16 + ji) * HID;
    short* d = Wr + (size_t)n * HID;
    for (int c = threadIdx.x; c < HID; c += 256) d[c] = f2bf(s[c]);
}

extern "C" void kernel_launch(void* const* d_in, const int* in_sizes, int n_in,
                              void* d_out, int out_size, void* d_ws, size_t ws_size,
                              hipStream_t stream) {
    const float* x    = (const float*)d_in[0];  // [B, T, IN_D]
    const float* W_ih = (const float*)d_in[1];  // [3H, IN_D]
    const float* b_ih = (const float*)d_in[2];
    const float* W_hh = (const float*)d_in[3];  // [3H, HID]
    const float* b_hh = (const float*)d_in[4];
    float* out = (float*)d_out;                 // [B, HID]

    char* p = (char*)d_ws;
    short* gx     = (short*)p;  p += (size_t)BT * G3 * 2;       // 251.7 MB, [t][b][3H]
    short* x_bf   = (short*)p;  p += (size_t)BT * IN_DP * 2;    //  52.4 MB, [t][b][640]
    short* hb0    = (short*)p;  p += (size_t)BATCH * HID * 2;   //   4.2 MB
    short* hb1    = (short*)p;  p += (size_t)BATCH * HID * 2;   //   4.2 MB
    short* Wih_r  = (short*)p;  p += (size_t)G3 * IN_DP * 2;    //   3.9 MB
    short* Whh_r  = (short*)p;  p += (size_t)G3 * HID * 2;      //   6.3 MB
    // total ~323 MB

    cvt_wih_r<<<G3, 256, 0, stream>>>(W_ih, Wih_r);
    cvt_whh<<<G3, 256, 0, stream>>>(W_hh, Whh_r);
    cvt_x<<<BT, 256, 0, stream>>>(x, x_bf);
    hipMemsetAsync(hb0, 0, (size_t)BATCH * HID * 2, stream);

    // Input projection, counted-vmcnt pipeline (5120 blocks x 512 threads)
    gemm_input2<<<5120, 512, 0, stream>>>(x_bf, Wih_r, b_ih, gx);

    // 20 fused recurrent steps (256 blocks x 512 threads, XCD-swizzled)
    for (int t = 0; t < TSTEP; ++t) {
        const short* hin = (t & 1) ? hb1 : hb0;
        short* hout      = (t & 1) ? hb0 : hb1;
        gru_step<<<256, 512, 0, stream>>>(hin, Whh_r, gx, b_hh,
                                          hout, out, t, t == TSTEP - 1 ? 1 : 0);
    }
}

// Round 12
// 734.222 us; speedup vs baseline: 1.8647x; 1.6961x over previous
//
#include <hip/hip_runtime.h>
#include <hip/hip_bf16.h>
#include <math.h>

#define HID   1024
#define IN_D  600
#define IN_DP 640      // 600 padded to 10 x BK=64 chunks
#define BATCH 2048
#define TSTEP 20
#define BT    (BATCH * TSTEP)   // 40960
#define G3    3072

typedef __attribute__((ext_vector_type(8))) short bf16x8;
typedef __attribute__((ext_vector_type(4))) float f32x4;
typedef __attribute__((ext_vector_type(4))) float fl4;
typedef __attribute__((ext_vector_type(4))) short sh4;

#define GLB(p) ((const __attribute__((address_space(1))) void*)(p))
#define LDS(p) ((__attribute__((address_space(3))) void*)(p))

__device__ __forceinline__ short f2bf(float f) {
    __hip_bfloat16 b = __float2bfloat16(f);
    return *(short*)&b;
}
__device__ __forceinline__ float bf2f(short s) {
    __hip_bfloat16 b = *(__hip_bfloat16*)&s;
    return __bfloat162float(b);
}

// ---------------------------------------------------------------------------
// Input projection v3: PERSISTENT-M counted-vmcnt pipeline.
// Round-8 ran 5120 blocks (20 sequential block-waves/CU), each paying a cold
// 2-chunk ramp + setup/teardown. v3: grid 256 (8 xcd x 2 jsub x 16 mgrp),
// each block loops 20 m-tiles (mblk = mgrp + 16*mt); the lead-2 pipeline
// stays full ACROSS m-tile boundaries (global chunk c = mt*10+kc, staged
// continuously). Ladder: vmcnt(10) steady; last tile kc=8 -> 5, kc=9 -> 0.
// Epilogue stores transiently inflate vmcnt; the next counted wait also
// drains them (stores are older than the waited loads) — safe by vmcnt
// semantics, costs ~1 store-ack per 10 chunks.
// Fragment code, swizzle, tile geometry IDENTICAL to round-8's gemm_input2
// (204 us, MfmaUtil 34%, conflicts 0).
// ---------------------------------------------------------------------------
__global__ __launch_bounds__(512) void gemm_input3(const short* __restrict__ X,
                                                   const short* __restrict__ Wih_r,
                                                   const float* __restrict__ b_ih,
                                                   short* __restrict__ gx) {
    __shared__ short LDSF[4 * 20480];   // buf b at b*20480: sA@0 (16K), sB@8192 (24K)

    const int id   = blockIdx.x;
    const int xcd  = id & 7;
    const int jsub = (id >> 3) & 1;
    const int mgrp = id >> 4;           // 0..15
    const int j0 = (xcd * 2 + jsub) * 64;

    const int tid  = threadIdx.x;
    const int wave = tid >> 6;          // 0..7
    const int lane = tid & 63;
    const int wm = (wave >> 2) * 64;    // m-group: 0 or 64
    const int jg = wave & 3;            // j-group: 16 j each
    const int fm = lane & 15;
    const int fq = lane >> 4;

    const int srow8 = lane >> 3;                // 0..7
    const int sxor  = ((lane & 7) ^ srow8) * 8; // inverse-swizzled col (shorts)

    const short* Wblk = Wih_r + (size_t)(j0 * 3) * IN_DP;   // 192 rows, K=640

    // 5 uniform global_load_lds per wave per chunk (2 sA + 3 sB)
    auto stage_m = [&](int m0, int kc, int bsel) {
        int k0 = kc * 64;
        short* base = LDSF + bsel * 20480;
#pragma unroll
        for (int i = 0; i < 2; ++i) {
            int row0 = wave * 16 + i * 8;
            const short* g = X + (size_t)(m0 + row0 + srow8) * IN_DP + k0 + sxor;
            __builtin_amdgcn_global_load_lds(GLB(g), LDS(base + row0 * 64), 16, 0, 0);
        }
#pragma unroll
        for (int i = 0; i < 3; ++i) {
            int row0 = wave * 24 + i * 8;
            const short* g = Wblk + (size_t)(row0 + srow8) * IN_DP + k0 + sxor;
            __builtin_amdgcn_global_load_lds(GLB(g), LDS(base + 8192 + row0 * 64), 16, 0, 0);
        }
    };

    const int jl = j0 + jg * 16 + fm;
    const float bias0 = b_ih[jl];
    const float bias1 = b_ih[HID + jl];
    const float bias2 = b_ih[2 * HID + jl];

    f32x4 acc[4][3] = {};    // [m-frag][gate]

    stage_m(mgrp * 128, 0, 0);
    stage_m(mgrp * 128, 1, 1);

    int cc = 0;                          // global chunk base = mt*10
#pragma unroll 1
    for (int mt = 0; mt < 20; ++mt) {
        const int m0cur = (mgrp + 16 * mt) * 128;
        const int m0nxt = (mgrp + 16 * (mt + 1)) * 128;   // unused at mt=19

#pragma unroll
        for (int kc = 0; kc < 10; ++kc) {
            if (kc < 8)        stage_m(m0cur, kc + 2, (cc + kc + 2) & 3);
            else if (mt < 19)  stage_m(m0nxt, kc - 8, (cc + kc + 2) & 3);

            if (kc < 8) {
                asm volatile("s_waitcnt vmcnt(10)" : : : "memory");
            } else if (mt < 19) {
                asm volatile("s_waitcnt vmcnt(10)" : : : "memory");
            } else if (kc == 8) {
                asm volatile("s_waitcnt vmcnt(5)"  : : : "memory");
            } else {
                asm volatile("s_waitcnt vmcnt(0)"  : : : "memory");
            }
            __builtin_amdgcn_s_barrier();
            __builtin_amdgcn_sched_barrier(0);

            short* buf = LDSF + ((cc + kc) & 3) * 20480;

#pragma unroll
            for (int kk = 0; kk < 2; ++kk) {
                bf16x8 af[4], bg[3];
                const int cbase = kk * 32 + fq * 8;
                const int csw = cbase ^ ((fm & 7) * 8);
#pragma unroll
                for (int mi = 0; mi < 4; ++mi)
                    af[mi] = *(const bf16x8*)(&buf[(wm + mi * 16 + fm) * 64 + csw]);
#pragma unroll
                for (int g = 0; g < 3; ++g)
                    bg[g] = *(const bf16x8*)(&buf[8192 + (jg * 48 + g * 16 + fm) * 64 + csw]);
                __builtin_amdgcn_s_setprio(1);
#pragma unroll
                for (int mi = 0; mi < 4; ++mi)
#pragma unroll
                    for (int g = 0; g < 3; ++g)
                        acc[mi][g] = __builtin_amdgcn_mfma_f32_16x16x32_bf16(af[mi], bg[g], acc[mi][g], 0, 0, 0);
                __builtin_amdgcn_s_setprio(0);
            }
        }

        // Epilogue for m-tile mt: gx[gm][g*1024 + jl]; then reset acc.
#pragma unroll
        for (int mi = 0; mi < 4; ++mi) {
#pragma unroll
            for (int r = 0; r < 4; ++r) {
                int gm = m0cur + wm + mi * 16 + fq * 4 + r;
                size_t rowb = (size_t)gm * G3;
                gx[rowb + jl]            = f2bf(acc[mi][0][r] + bias0);
                gx[rowb + HID + jl]      = f2bf(acc[mi][1][r] + bias1);
                gx[rowb + 2 * HID + jl]  = f2bf(acc[mi][2][r] + bias2);
            }
        }
#pragma unroll
        for (int mi = 0; mi < 4; ++mi)
#pragma unroll
            for (int g = 0; g < 3; ++g)
                acc[mi][g] = (f32x4){0.f, 0.f, 0.f, 0.f};

        cc += 10;
    }
}

// ---------------------------------------------------------------------------
// Fused recurrent step v7 (VERBATIM round-8 build — best measured, 795 us
// total. af-direct-global (v12/v13) refuted twice: LDS-staged A beats
// register-direct global A for this tile despite 2x LDS reads).
// Counted-vmcnt pipeline: issue -> vmcnt(N) -> s_barrier -> read, NB=4.
// ---------------------------------------------------------------------------
__global__ __launch_bounds__(512) void gru_step(const short* __restrict__ hb_in,
                                                const short* __restrict__ Wr,
                                                const short* __restrict__ gx,
                                                const float* __restrict__ b_hh,
                                                short* __restrict__ hb_out,
                                                float* __restrict__ out,
                                                int t, int last) {
    __shared__ short LDSF[4 * 20480];   // 160 KB: buf b at b*20480 (sA@0, sB@8192)
                                        // sGX tail-overlay at [0 .. 24576)

    const int id   = blockIdx.x;
    const int xcd  = id & 7;
    const int rest = id >> 3;           // 0..31
    const int jsub = rest & 1;
    const int mblk = rest >> 1;         // 0..15
    const int j0 = (xcd * 2 + jsub) * 64;
    const int m0 = mblk * 128;
    const int hchunk = j0 >> 6;         // k-chunk holding h[:, j0..j0+63]

    const int tid  = threadIdx.x;
    const int wave = tid >> 6;          // 0..7
    const int lane = tid & 63;
    const int wm = (wave >> 2) * 64;    // m-group: 0 or 64
    const int jg = wave & 3;            // j-group: 16 j each
    const int fm = lane & 15;
    const int fq = lane >> 4;

    const int srow8 = lane >> 3;               // 0..7 (row within 8-row group)
    const int sxor  = ((lane & 7) ^ srow8) * 8; // inverse-swizzled col (shorts)

    const short* Wblk = Wr + (size_t)(j0 * 3) * HID;   // 192 rows, K=1024
    const short* gxt  = gx + (size_t)t * BATCH * G3;

    f32x4 acc[4][3] = {};    // [m-frag][gate]
    short hsnap[4][4];       // h[m-frag rows][this lane's j]

    // 5 global_load_lds per wave per chunk — UNIFORM across waves (vmcnt is
    // per-wave; the counted schedule requires symmetric issue counts).
    auto stage = [&](int kc, int bsel) {
        int k0 = kc * 64;
        short* base = LDSF + bsel * 20480;
#pragma unroll
        for (int i = 0; i < 2; ++i) {   // sA: 16 instrs over 8 waves
            int row0 = wave * 16 + i * 8;
            const short* g = hb_in + (size_t)(m0 + row0 + srow8) * HID + k0 + sxor;
            __builtin_amdgcn_global_load_lds(GLB(g), LDS(base + row0 * 64), 16, 0, 0);
        }
#pragma unroll
        for (int i = 0; i < 3; ++i) {   // sB: 24 instrs over 8 waves
            int row0 = wave * 24 + i * 8;
            const short* g = Wblk + (size_t)(row0 + srow8) * HID + k0 + sxor;
            __builtin_amdgcn_global_load_lds(GLB(g), LDS(base + 8192 + row0 * 64), 16, 0, 0);
        }
    };
    // sGX instr q (0..47): gate q>>4, rows (q&15)*8..+7, 64 swizzled j cols,
    // dest = LDSF + q*512 (buf0 + buf1 head).
    auto sgx_load = [&](int q) {
        int g = q >> 4;
        int row0 = (q & 15) * 8;
        const short* src = gxt + (size_t)(m0 + row0 + srow8) * G3 + g * HID + j0 + sxor;
        __builtin_amdgcn_global_load_lds(GLB(src), LDS(LDSF + q * 512), 16, 0, 0);
    };

    const int jj = jg * 16 + fm;        // block-local j (0..63)

    stage(0, 0);
    stage(1, 1);

#pragma unroll
    for (int ic = 0; ic < 16; ++ic) {
        // ---- issue (writes a buffer whose readers finished >=2 barriers ago)
        if (ic < 14) {
            stage(ic + 2, (ic + 2) & 3);          // 5 loads/wave
        } else if (ic == 14) {
#pragma unroll
            for (int i = 0; i < 5; ++i) sgx_load(wave * 5 + i);   // 40KB -> buf0
        } else {
            sgx_load(40 + wave);                  // 8KB -> buf1 head, 1/wave
        }
        // ---- counted wait on OWN chunk-ic loads, THEN publish via barrier.
        if (ic < 15) asm volatile("s_waitcnt vmcnt(10)" : : : "memory");
        else         asm volatile("s_waitcnt vmcnt(6)"  : : : "memory");
        __builtin_amdgcn_s_barrier();
        __builtin_amdgcn_sched_barrier(0);        // no reads hoist above publish

        short* buf = LDSF + (ic & 3) * 20480;

        if (ic == hchunk) {              // snapshot h[:, j0..j0+63] from sA
#pragma unroll
            for (int mi = 0; mi < 4; ++mi)
#pragma unroll
                for (int r = 0; r < 4; ++r) {
                    int mrow = wm + mi * 16 + fq * 4 + r;
                    hsnap[mi][r] = buf[mrow * 64 + (jj ^ ((mrow & 7) * 8))];
                }
        }

#pragma unroll
        for (int kk = 0; kk < 2; ++kk) {
            bf16x8 af[4], bg[3];
            const int cbase = kk * 32 + fq * 8;
            const int csw = cbase ^ ((fm & 7) * 8);   // swizzled read col
#pragma unroll
            for (int mi = 0; mi < 4; ++mi)
                af[mi] = *(const bf16x8*)(&buf[(wm + mi * 16 + fm) * 64 + csw]);
#pragma unroll
            for (int g = 0; g < 3; ++g)
                bg[g] = *(const bf16x8*)(&buf[8192 + (jg * 48 + g * 16 + fm) * 64 + csw]);
            __builtin_amdgcn_s_setprio(1);
#pragma unroll
            for (int mi = 0; mi < 4; ++mi)
#pragma unroll
                for (int g = 0; g < 3; ++g)
                    acc[mi][g] = __builtin_amdgcn_mfma_f32_16x16x32_bf16(af[mi], bg[g], acc[mi][g], 0, 0, 0);
            __builtin_amdgcn_s_setprio(0);
        }
    }

    // Drain sGX (only remaining outstanding loads), publish, then the
    // epilogue is LDS/register-only inputs; global STORES only.
    asm volatile("s_waitcnt vmcnt(0)" : : : "memory");
    __builtin_amdgcn_s_barrier();
    __builtin_amdgcn_sched_barrier(0);

    const short* sGX = LDSF;            // [0 .. 24576) shorts
    const int jlane = j0 + jj;
    const float bh_r = b_hh[jlane];
    const float bh_i = b_hh[HID + jlane];
    const float bh_n = b_hh[2 * HID + jlane];

#pragma unroll
    for (int mi = 0; mi < 4; ++mi) {
#pragma unroll
        for (int r = 0; r < 4; ++r) {
            int mloc = wm + mi * 16 + fq * 4 + r;
            int gm = m0 + mloc;
            int jsw = jj ^ ((mloc & 7) * 8);          // sGX swizzled col
            float xr = bf2f(sGX[        mloc * 64 + jsw]);
            float xi = bf2f(sGX[ 8192 + mloc * 64 + jsw]);
            float xn = bf2f(sGX[16384 + mloc * 64 + jsw]);

            float rg = 1.0f / (1.0f + __expf(-(xr + acc[mi][0][r] + bh_r)));
            float ig = 1.0f / (1.0f + __expf(-(xi + acc[mi][1][r] + bh_i)));
            float ng = tanhf(xn + rg * (acc[mi][2][r] + bh_n));

            float h  = bf2f(hsnap[mi][r]);
            float hy = ng + ig * (h - ng);
            size_t idx = (size_t)gm * HID + jlane;
            hb_out[idx] = f2bf(hy);
            if (last) out[idx] = hy;
        }
    }
}

// x [b][t][600] fp32 -> x_bf [t*B + b][640] bf16 zero-padded (transpose).
// Vectorized (G13): 1 float4 load + 1 short4 store per thread.
__global__ __launch_bounds__(192) void cvt_x(const float* __restrict__ X, short* __restrict__ Xb) {
    int rd = blockIdx.x;             // dst row = t*BATCH + b
    int tt = rd >> 11;               // /2048
    int b  = rd & (BATCH - 1);
    const float* s = X + ((size_t)b * TSTEP + tt) * IN_D;
    short* d = Xb + (size_t)rd * IN_DP;
    int c = threadIdx.x;             // 0..191; 150 f4 of data + 10 s4 pad
    if (c < 150) {
        fl4 v = *(const fl4*)(s + c * 4);
        sh4 o = { f2bf(v[0]), f2bf(v[1]), f2bf(v[2]), f2bf(v[3]) };
        *(sh4*)(d + c * 4) = o;
    } else if (c < 160) {
        *(sh4*)(d + c * 4) = (sh4){0, 0, 0, 0};
    }
}

// W_ih -> gate-block-interleaved bf16 [3072][640] (vectorized):
// dst row jb*48+g*16+ji = W_ih[g*1024 + jb*16 + ji], zero-padded K 600->640
__global__ __launch_bounds__(192) void cvt_wih_r(const float* __restrict__ W, short* __restrict__ Wb) {
    int n  = blockIdx.x;             // dst row 0..3071
    int jb = n / 48;
    int rem = n - jb * 48;
    int g  = rem >> 4;
    int ji = rem & 15;
    const float* s = W + (size_t)(g * HID + jb * 16 + ji) * IN_D;
    short* d = Wb + (size_t)n * IN_DP;
    int c = threadIdx.x;
    if (c < 150) {
        fl4 v = *(const fl4*)(s + c * 4);
        sh4 o = { f2bf(v[0]), f2bf(v[1]), f2bf(v[2]), f2bf(v[3]) };
        *(sh4*)(d + c * 4) = o;
    } else if (c < 160) {
        *(sh4*)(d + c * 4) = (sh4){0, 0, 0, 0};
    }
}

// W_hh -> Wr gate-block-interleaved bf16 (vectorized):
// Wr[jb*48+g*16+ji] = Whh[g*1024+jb*16+ji]
__global__ __launch_bounds__(256) void cvt_whh(const float* __restrict__ W, short* __restrict__ Wr) {
    int n  = blockIdx.x;             // dst row 0..3071
    int jb = n / 48;
    int rem = n - jb * 48;
    int g  = rem >> 4;
    int ji = rem & 15;
    const float* s = W + (size_t)(g * HID + jb * 16 + ji) * HID;
    short* d = Wr + (size_t)n * HID;
    int c = threadIdx.x;             // 256 f4 = 1024 cols exactly
    fl4 v = *(const fl4*)(s + c * 4);
    sh4 o = { f2bf(v[0]), f2bf(v[1]), f2bf(v[2]), f2bf(v[3]) };
    *(sh4*)(d + c * 4) = o;
}

extern "C" void kernel_launch(void* const* d_in, const int* in_sizes, int n_in,
                              void* d_out, int out_size, void* d_ws, size_t ws_size,
                              hipStream_t stream) {
    const float* x    = (const float*)d_in[0];  // [B, T, IN_D]
    const float* W_ih = (const float*)d_in[1];  // [3H, IN_D]
    const float* b_ih = (const float*)d_in[2];
    const float* W_hh = (const float*)d_in[3];  // [3H, HID]
    const float* b_hh = (const float*)d_in[4];
    float* out = (float*)d_out;                 // [B, HID]

    char* p = (char*)d_ws;
    short* gx     = (short*)p;  p += (size_t)BT * G3 * 2;       // 251.7 MB, [t][b][3H]
    short* x_bf   = (short*)p;  p += (size_t)BT * IN_DP * 2;    //  52.4 MB, [t][b][640]
    short* hb0    = (short*)p;  p += (size_t)BATCH * HID * 2;   //   4.2 MB
    short* hb1    = (short*)p;  p += (size_t)BATCH * HID * 2;   //   4.2 MB
    short* Wih_r  = (short*)p;  p += (size_t)G3 * IN_DP * 2;    //   3.9 MB
    short* Whh_r  = (short*)p;  p += (size_t)G3 * HID * 2;      //   6.3 MB
    // total ~323 MB

    cvt_wih_r<<<G3, 192, 0, stream>>>(W_ih, Wih_r);
    cvt_whh<<<G3, 256, 0, stream>>>(W_hh, Whh_r);
    cvt_x<<<BT, 192, 0, stream>>>(x, x_bf);
    hipMemsetAsync(hb0, 0, (size_t)BATCH * HID * 2, stream);

    // Input projection: persistent-m pipeline (256 blocks x 512 threads,
    // 20 m-tiles per block, pipeline continuous across tiles)
    gemm_input3<<<256, 512, 0, stream>>>(x_bf, Wih_r, b_ih, gx);

    // 20 fused recurrent steps (256 blocks x 512 threads, XCD-swizzled)
    for (int t = 0; t < TSTEP; ++t) {
        const short* hin = (t & 1) ? hb1 : hb0;
        short* hout      = (t & 1) ? hb0 : hb1;
        gru_step<<<256, 512, 0, stream>>>(hin, Whh_r, gx, b_hh,
                                          hout, out, t, t == TSTEP - 1 ? 1 : 0);
    }
}